// Round 17
// baseline (268.685 us; speedup 1.0000x reference)
//
#include <hip/hip_runtime.h>
#include <cstdint>
#include <cstddef>

#define N_NODES 100000
#define N_EDGES 300000
#define N_GRAPHS 2000
#define HID 256
#define INDIM 82
#define XCPAD 84     // compact bf16 x row (82 + 2 pad), 168 B
#define K1PAD 128
#define N_TILES ((N_NODES + 255) / 256)  // 391
#define GEMM_GRID (((N_TILES + 7) / 8) * 16)  // 784: XCD-paired half-tiles
#define SCAN_CHUNK 2048
#define NBLK_SCAN ((N_NODES + SCAN_CHUNK - 1) / SCAN_CHUNK)  // 49

typedef __bf16 bf16x8 __attribute__((ext_vector_type(8)));
typedef float f32x4 __attribute__((ext_vector_type(4)));

// native conversion: compiler emits v_cvt_pk_bf16_f32 (RNE) — do NOT hand-write bit math
__device__ __forceinline__ unsigned short f2bf(float f) {
    union { __bf16 h; unsigned short u; } v;
    v.h = (__bf16)f;
    return v.u;
}
__device__ __forceinline__ float bf2f(unsigned short s) {
    return __uint_as_float(((unsigned int)s) << 16);
}
// involution on [0,256): position p holds logical column sig(p) in sigma-space buffers
__device__ __forceinline__ int sig(int c) { return ((c & 15) << 4) | (c >> 4); }

// ---------------- degree counting ----------------
__global__ void k_cnt_acc(const int* __restrict__ ei, int* cnt) {
    int e = blockIdx.x * 256 + threadIdx.x;
    if (e < N_EDGES) atomicAdd(&cnt[ei[N_EDGES + e]], 1);
}

// ---------------- exclusive prefix sum ----------------
__global__ __launch_bounds__(256) void k_scan1(const int* __restrict__ cnt, int* __restrict__ off,
                                               int* __restrict__ partial) {
    __shared__ int sdata[256];
    const int base = blockIdx.x * SCAN_CHUNK;
    const int t = threadIdx.x;
    int v[8];
    int s = 0;
#pragma unroll
    for (int i = 0; i < 8; ++i) {
        int idx = base + t * 8 + i;
        v[i] = (idx < N_NODES) ? cnt[idx] : 0;
        s += v[i];
    }
    sdata[t] = s;
    __syncthreads();
    for (int d = 1; d < 256; d <<= 1) {
        int x = (t >= d) ? sdata[t - d] : 0;
        __syncthreads();
        sdata[t] += x;
        __syncthreads();
    }
    int run = sdata[t] - s;
#pragma unroll
    for (int i = 0; i < 8; ++i) {
        int idx = base + t * 8 + i;
        if (idx < N_NODES) off[idx] = run;
        run += v[i];
    }
    if (t == 255) partial[blockIdx.x] = sdata[255];
}

__global__ void k_scan2(int* partial) {
    if (threadIdx.x == 0 && blockIdx.x == 0) {
        int run = 0;
        for (int i = 0; i < NBLK_SCAN; ++i) {
            int v = partial[i];
            partial[i] = run;
            run += v;
        }
    }
}

// scan fixup + cur init + dinv (merged)
__global__ void k_scan3(int* __restrict__ off, const int* __restrict__ partial,
                        int* __restrict__ cur, const int* __restrict__ cnt,
                        float* __restrict__ dinv) {
    int i = blockIdx.x * 256 + threadIdx.x;
    if (i < N_NODES) {
        int o = off[i] + partial[i >> 11];
        off[i] = o;
        cur[i] = o;
        dinv[i] = rsqrtf((float)cnt[i] + 1.0f);
    }
}

// CSR fill with precomputed edge norm
__global__ void k_fill(const int* __restrict__ ei, const float* __restrict__ dinv, int* cur,
                       int* __restrict__ csr_src, float* __restrict__ csr_norm) {
    int e = blockIdx.x * 256 + threadIdx.x;
    if (e < N_EDGES) {
        int s = ei[e];
        int d = ei[N_EDGES + e];
        int pos = atomicAdd(&cur[d], 1);
        csr_src[pos] = s;
        csr_norm[pos] = dinv[s] * dinv[d];
    }
}

// ---------------- merged prep: wconv x3 + graph bounds + x conversion ----------------
// PERM: Wb slot k (position-space) sources W[sig(k)] — matches sigma-space A rows.
__device__ __forceinline__ void wconv_body(const float* __restrict__ W,
                                           unsigned short* __restrict__ Wb, int KSRC, int i,
                                           bool perm) {
    // Wb fragment-contiguous: [kc][nt][lg][lr][j]; holds W[ksrc(kc*32+lg*8+j)][nt*16+lr]
    int kc = i >> 13;
    int r = i & 8191;
    int nt = r >> 9;
    int r2 = r & 511;
    int lg = r2 >> 7;
    int lr = (r2 >> 3) & 15;
    int j = r2 & 7;
    int k = kc * 32 + lg * 8 + j;
    if (perm) k = sig(k);
    int n = nt * 16 + lr;
    Wb[i] = (k < KSRC) ? f2bf(W[(size_t)k * HID + n]) : (unsigned short)0;
}

#define PREP_W1 128                      // 256*K1PAD/256
#define PREP_W23 256                     // 256*HID/256
#define PREP_BND 8                       // ceil(2001/256)
#define PREP_XC ((N_NODES * XCPAD + 255) / 256)
#define PREP_BLOCKS (PREP_W1 + 2 * PREP_W23 + PREP_BND + PREP_XC)

__global__ void k_prep(const float* __restrict__ x, unsigned short* __restrict__ xc,
                       const float* __restrict__ W1, unsigned short* __restrict__ Wb1,
                       const float* __restrict__ W2, unsigned short* __restrict__ Wb2,
                       const float* __restrict__ W3, unsigned short* __restrict__ Wb3,
                       const int* __restrict__ batch, int* __restrict__ gstart) {
    int b = blockIdx.x;
    int t = threadIdx.x;
    if (b < PREP_W1) { wconv_body(W1, Wb1, INDIM, b * 256 + t, false); return; }
    b -= PREP_W1;
    if (b < PREP_W23) { wconv_body(W2, Wb2, HID, b * 256 + t, true); return; }
    b -= PREP_W23;
    if (b < PREP_W23) { wconv_body(W3, Wb3, HID, b * 256 + t, true); return; }
    b -= PREP_W23;
    if (b < PREP_BND) {
        int g = b * 256 + t;
        if (g <= N_GRAPHS) {
            int lo = 0, hi = N_NODES;
            while (lo < hi) {
                int mid = (lo + hi) >> 1;
                if (batch[mid] < g) lo = mid + 1;
                else hi = mid;
            }
            gstart[g] = lo;
        }
        return;
    }
    b -= PREP_BND;
    int i = b * 256 + t;
    if (i < N_NODES * XCPAD) {
        int node = i / XCPAD;
        int k = i - node * XCPAD;
        xc[i] = (k < INDIM) ? f2bf(x[(size_t)node * INDIM + k]) : (unsigned short)0;
    }
}

// ---------------- MFMA GEMM (XCD-paired half-W): Cb = relu(A @ W + b), sigma-space C ----
// grid = GEMM_GRID; block b -> col-half h=(b>>3)&1, tile t=(b&7)|((b>>4)<<3).
// Blocks b and b+8 (the two halves of tile t) land on the SAME XCD (round-robin %8),
// so A is fetched once into that XCD's L2 (fixes R12's cross-XCD double-fetch).
// Half of W in LDS: 64 KB (K=256) -> 2 blocks/CU = 4 waves/SIMD under
// __launch_bounds__(512,4) (VGPR cap 128; demand ~105: acc 64 + per-kc A 8 + misc).
// A loaded per-kc (streaming): 4 waves/SIMD + L2-paired A covers the latency.
// Epilogue: logical col h*128+nt*16+lr -> sigma position lr*16+h*8+nt: one 16 B store/row.
template <int K>
__global__ __launch_bounds__(512, 4) void k_gemm_mfma(const unsigned short* __restrict__ A,
                                                      const unsigned short* __restrict__ Wb,
                                                      const float* __restrict__ bias,
                                                      unsigned short* __restrict__ Cb) {
    constexpr int NK = K / 32;
    __shared__ __align__(16) unsigned short Wsh[K * 128];  // 32 KB (K=128) / 64 KB (K=256)

    const int b = blockIdx.x;
    const int h = (b >> 3) & 1;
    const int t = (b & 7) | ((b >> 4) << 3);
    if (t >= N_TILES) return;  // uniform per block: safe before barrier

    const int tid = threadIdx.x;
    const int w = tid >> 6;
    const int l = tid & 63;
    const int lr = l & 15;
    const int lg = l >> 4;

    // stage this column-half of W: per kc, nt range [h*8, h*8+8) = 4096 contiguous shorts
#pragma unroll
    for (int i = 0; i < NK; ++i) {
        *reinterpret_cast<uint4*>(&Wsh[i * 4096 + tid * 8]) =
            *reinterpret_cast<const uint4*>(Wb + i * 8192 + h * 4096 + tid * 8);
    }
    __syncthreads();

    float bv[8];
#pragma unroll
    for (int nt = 0; nt < 8; ++nt) bv[nt] = bias[h * 128 + nt * 16 + lr];

    const int rowbase = t * 256 + w * 32;
    int r0 = rowbase + lr;
    int r1 = rowbase + 16 + lr;
    int r0c = r0 < N_NODES ? r0 : (N_NODES - 1);
    int r1c = r1 < N_NODES ? r1 : (N_NODES - 1);
    const unsigned short* a0p = A + (size_t)r0c * K + lg * 8;
    const unsigned short* a1p = A + (size_t)r1c * K + lg * 8;

    f32x4 acc0[8] = {};
    f32x4 acc1[8] = {};

#pragma unroll
    for (int kc = 0; kc < NK; ++kc) {
        bf16x8 a0 = *reinterpret_cast<const bf16x8*>(a0p + kc * 32);
        bf16x8 a1 = *reinterpret_cast<const bf16x8*>(a1p + kc * 32);
        const unsigned short* bfp = Wsh + kc * 4096 + l * 8;
#pragma unroll
        for (int nt = 0; nt < 8; ++nt) {
            bf16x8 bb = *reinterpret_cast<const bf16x8*>(bfp + nt * 512);
            acc0[nt] = __builtin_amdgcn_mfma_f32_16x16x32_bf16(a0, bb, acc0[nt], 0, 0, 0);
            acc1[nt] = __builtin_amdgcn_mfma_f32_16x16x32_bf16(a1, bb, acc1[nt], 0, 0, 0);
        }
    }

    // MFMA C layout: logical col = h*128+nt*16+lr, row = (lane>>4)*4 + j.
    // Sigma position = lr*16 + h*8 + nt -> 16 B contiguous per lane per row.
    int gr0 = rowbase + lg * 4;
#pragma unroll
    for (int j = 0; j < 4; ++j) {
        int gr = gr0 + j;
        if (gr < N_NODES) {
            unsigned short t0[8];
#pragma unroll
            for (int nt = 0; nt < 8; ++nt)
                t0[nt] = f2bf(fmaxf(acc0[nt][j] + bv[nt], 0.0f));
            *reinterpret_cast<uint4*>(Cb + (size_t)gr * HID + lr * 16 + h * 8) =
                *reinterpret_cast<const uint4*>(t0);
        }
        int gr2 = gr + 16;
        if (gr2 < N_NODES) {
            unsigned short t1[8];
#pragma unroll
            for (int nt = 0; nt < 8; ++nt)
                t1[nt] = f2bf(fmaxf(acc1[nt][j] + bv[nt], 0.0f));
            *reinterpret_cast<uint4*>(Cb + (size_t)gr2 * HID + lr * 16 + h * 8) =
                *reinterpret_cast<const uint4*>(t1);
        }
    }
}

// ---------------- aggregate: ob = bf16(dinv^2*in_self + sum norm*in[src]) ----------------
// Position-wise (works identically in sigma-space). At the 6.3 TB/s logical streaming
// ceiling (measured R9/R10) — do not touch.
__global__ void k_aggregate256(const unsigned short* __restrict__ tb,
                               const float* __restrict__ dinv, const int* __restrict__ off,
                               const int* __restrict__ cnt, const int* __restrict__ csr_src,
                               const float* __restrict__ csr_norm,
                               unsigned short* __restrict__ ob) {
    int node = blockIdx.x * 4 + (threadIdx.x >> 6);
    if (node >= N_NODES) return;
    int lane = threadIdx.x & 63;
    const size_t lo = (size_t)lane * 4;
    int o0 = off[node];
    int n = cnt[node];
    float di = dinv[node];
    float s2 = di * di;
    ushort4 sv = *reinterpret_cast<const ushort4*>(&tb[(size_t)node * HID + lo]);
    float4 acc = {bf2f(sv.x) * s2, bf2f(sv.y) * s2, bf2f(sv.z) * s2, bf2f(sv.w) * s2};

    int j = 0;
    for (; j + 3 < n; j += 4) {
        int s0 = csr_src[o0 + j];
        int s1 = csr_src[o0 + j + 1];
        int s2i = csr_src[o0 + j + 2];
        int s3 = csr_src[o0 + j + 3];
        float n0 = csr_norm[o0 + j];
        float n1 = csr_norm[o0 + j + 1];
        float n2 = csr_norm[o0 + j + 2];
        float n3 = csr_norm[o0 + j + 3];
        ushort4 u0 = *reinterpret_cast<const ushort4*>(&tb[(size_t)s0 * HID + lo]);
        ushort4 u1 = *reinterpret_cast<const ushort4*>(&tb[(size_t)s1 * HID + lo]);
        ushort4 u2 = *reinterpret_cast<const ushort4*>(&tb[(size_t)s2i * HID + lo]);
        ushort4 u3 = *reinterpret_cast<const ushort4*>(&tb[(size_t)s3 * HID + lo]);
        acc.x = fmaf(n0, bf2f(u0.x), acc.x); acc.y = fmaf(n0, bf2f(u0.y), acc.y);
        acc.z = fmaf(n0, bf2f(u0.z), acc.z); acc.w = fmaf(n0, bf2f(u0.w), acc.w);
        acc.x = fmaf(n1, bf2f(u1.x), acc.x); acc.y = fmaf(n1, bf2f(u1.y), acc.y);
        acc.z = fmaf(n1, bf2f(u1.z), acc.z); acc.w = fmaf(n1, bf2f(u1.w), acc.w);
        acc.x = fmaf(n2, bf2f(u2.x), acc.x); acc.y = fmaf(n2, bf2f(u2.y), acc.y);
        acc.z = fmaf(n2, bf2f(u2.z), acc.z); acc.w = fmaf(n2, bf2f(u2.w), acc.w);
        acc.x = fmaf(n3, bf2f(u3.x), acc.x); acc.y = fmaf(n3, bf2f(u3.y), acc.y);
        acc.z = fmaf(n3, bf2f(u3.z), acc.z); acc.w = fmaf(n3, bf2f(u3.w), acc.w);
    }
    int rem = n - j;
    if (rem & 2) {
        int s0 = csr_src[o0 + j];
        int s1 = csr_src[o0 + j + 1];
        float n0 = csr_norm[o0 + j];
        float n1 = csr_norm[o0 + j + 1];
        ushort4 u0 = *reinterpret_cast<const ushort4*>(&tb[(size_t)s0 * HID + lo]);
        ushort4 u1 = *reinterpret_cast<const ushort4*>(&tb[(size_t)s1 * HID + lo]);
        acc.x = fmaf(n0, bf2f(u0.x), acc.x); acc.y = fmaf(n0, bf2f(u0.y), acc.y);
        acc.z = fmaf(n0, bf2f(u0.z), acc.z); acc.w = fmaf(n0, bf2f(u0.w), acc.w);
        acc.x = fmaf(n1, bf2f(u1.x), acc.x); acc.y = fmaf(n1, bf2f(u1.y), acc.y);
        acc.z = fmaf(n1, bf2f(u1.z), acc.z); acc.w = fmaf(n1, bf2f(u1.w), acc.w);
        j += 2;
    }
    if (rem & 1) {
        int s0 = csr_src[o0 + j];
        float n0 = csr_norm[o0 + j];
        ushort4 u0 = *reinterpret_cast<const ushort4*>(&tb[(size_t)s0 * HID + lo]);
        acc.x = fmaf(n0, bf2f(u0.x), acc.x); acc.y = fmaf(n0, bf2f(u0.y), acc.y);
        acc.z = fmaf(n0, bf2f(u0.z), acc.z); acc.w = fmaf(n0, bf2f(u0.w), acc.w);
    }
    ushort4 o;
    o.x = f2bf(acc.x);
    o.y = f2bf(acc.y);
    o.z = f2bf(acc.z);
    o.w = f2bf(acc.w);
    *reinterpret_cast<ushort4*>(&ob[(size_t)node * HID + lo]) = o;
}

// layer-1: aggregate compact bf16 x [N,84] -> padded bf16 [N,128] GEMM input (linear k)
__global__ void k_aggx(const unsigned short* __restrict__ xc,
                       const float* __restrict__ dinv, const int* __restrict__ off,
                       const int* __restrict__ cnt, const int* __restrict__ csr_src,
                       const float* __restrict__ csr_norm,
                       unsigned short* __restrict__ ob) {
    int node = blockIdx.x * 4 + (threadIdx.x >> 6);
    if (node >= N_NODES) return;
    int lane = threadIdx.x & 63;
    const bool act = lane < (XCPAD / 2);  // 42 lanes cover 84 cols
    const size_t co = (size_t)lane * 2;
    int o0 = off[node];
    int n = cnt[node];
    float di = dinv[node];
    float s2 = di * di;
    float2 acc = {0.0f, 0.0f};
    if (act) {
        ushort2 sv = *reinterpret_cast<const ushort2*>(&xc[(size_t)node * XCPAD + co]);
        acc.x = bf2f(sv.x) * s2;
        acc.y = bf2f(sv.y) * s2;
    }
    int j = 0;
    for (; j + 3 < n; j += 4) {
        int s0 = csr_src[o0 + j];
        int s1 = csr_src[o0 + j + 1];
        int s2i = csr_src[o0 + j + 2];
        int s3 = csr_src[o0 + j + 3];
        float n0 = csr_norm[o0 + j];
        float n1 = csr_norm[o0 + j + 1];
        float n2 = csr_norm[o0 + j + 2];
        float n3 = csr_norm[o0 + j + 3];
        if (act) {
            ushort2 u0 = *reinterpret_cast<const ushort2*>(&xc[(size_t)s0 * XCPAD + co]);
            ushort2 u1 = *reinterpret_cast<const ushort2*>(&xc[(size_t)s1 * XCPAD + co]);
            ushort2 u2 = *reinterpret_cast<const ushort2*>(&xc[(size_t)s2i * XCPAD + co]);
            ushort2 u3 = *reinterpret_cast<const ushort2*>(&xc[(size_t)s3 * XCPAD + co]);
            acc.x = fmaf(n0, bf2f(u0.x), acc.x); acc.y = fmaf(n0, bf2f(u0.y), acc.y);
            acc.x = fmaf(n1, bf2f(u1.x), acc.x); acc.y = fmaf(n1, bf2f(u1.y), acc.y);
            acc.x = fmaf(n2, bf2f(u2.x), acc.x); acc.y = fmaf(n2, bf2f(u2.y), acc.y);
            acc.x = fmaf(n3, bf2f(u3.x), acc.x); acc.y = fmaf(n3, bf2f(u3.y), acc.y);
        }
    }
    int rem = n - j;
    if (rem & 2) {
        int s0 = csr_src[o0 + j];
        int s1 = csr_src[o0 + j + 1];
        float n0 = csr_norm[o0 + j];
        float n1 = csr_norm[o0 + j + 1];
        if (act) {
            ushort2 u0 = *reinterpret_cast<const ushort2*>(&xc[(size_t)s0 * XCPAD + co]);
            ushort2 u1 = *reinterpret_cast<const ushort2*>(&xc[(size_t)s1 * XCPAD + co]);
            acc.x = fmaf(n0, bf2f(u0.x), acc.x); acc.y = fmaf(n0, bf2f(u0.y), acc.y);
            acc.x = fmaf(n1, bf2f(u1.x), acc.x); acc.y = fmaf(n1, bf2f(u1.y), acc.y);
        }
        j += 2;
    }
    if (rem & 1) {
        int s0 = csr_src[o0 + j];
        float n0 = csr_norm[o0 + j];
        if (act) {
            ushort2 u0 = *reinterpret_cast<const ushort2*>(&xc[(size_t)s0 * XCPAD + co]);
            acc.x = fmaf(n0, bf2f(u0.x), acc.x); acc.y = fmaf(n0, bf2f(u0.y), acc.y);
        }
    }
    ushort2 o;
    o.x = f2bf(acc.x);
    o.y = f2bf(acc.y);
    *reinterpret_cast<ushort2*>(&ob[(size_t)node * K1PAD + co]) = o;  // all 64 lanes: pad zeroed
}

// ---------------- pool: 2 waves per graph; input sigma-space, output linear ----------------
__global__ void k_pool2(const unsigned short* __restrict__ hb, const int* __restrict__ gstart,
                        float* __restrict__ out) {
    int g = blockIdx.x;
    int w = threadIdx.x >> 6;
    int lane = threadIdx.x & 63;
    int p = w * 128 + lane * 2;  // position in sigma-space
    int s = gstart[g], e = gstart[g + 1];
    float2 m = {0.0f, 0.0f};  // h >= 0 after relu
    for (int i = s; i < e; ++i) {
        ushort2 u = *reinterpret_cast<const ushort2*>(&hb[(size_t)i * HID + p]);
        m.x = fmaxf(m.x, bf2f(u.x));
        m.y = fmaxf(m.y, bf2f(u.y));
    }
    // un-permute: position p holds logical column sig(p)
    out[(size_t)g * HID + sig(p)] = m.x;
    out[(size_t)g * HID + sig(p + 1)] = m.y;
}

extern "C" void kernel_launch(void* const* d_in, const int* in_sizes, int n_in,
                              void* d_out, int out_size, void* d_ws, size_t ws_size,
                              hipStream_t stream) {
    const float* x = (const float*)d_in[0];
    const int* ei = (const int*)d_in[1];
    const int* batch = (const int*)d_in[2];
    const float* W1 = (const float*)d_in[4];
    const float* b1 = (const float*)d_in[5];
    const float* W2 = (const float*)d_in[6];
    const float* b2 = (const float*)d_in[7];
    const float* W3 = (const float*)d_in[8];
    const float* b3 = (const float*)d_in[9];
    float* out = (float*)d_out;

    // workspace layout (~150 MB, R10-proven)
    char* ws = (char*)d_ws;
    float* dinv = (float*)(ws);
    int* cnt = (int*)(ws + (512 << 10));
    int* off = (int*)(ws + (1024 << 10));
    int* cur = (int*)(ws + (1536 << 10));
    int* part = (int*)(ws + (2048 << 10));
    int* gstart = (int*)(ws + (2048 << 10) + 4096);
    int* csr_src = (int*)(ws + (2176 << 10));        // 1.2 MB
    float* csr_norm = (float*)(ws + (3392 << 10));   // 1.2 MB
    unsigned short* Wb1 = (unsigned short*)(ws + (4608 << 10));   // 64 KB
    unsigned short* Wb2 = (unsigned short*)(ws + (4736 << 10));   // 128 KB
    unsigned short* Wb3 = (unsigned short*)(ws + (4928 << 10));   // 128 KB
    unsigned short* ag1_b = (unsigned short*)(ws + (5120 << 10));               // 25.6 MB
    unsigned short* bufA = (unsigned short*)(ws + (5120 << 10) + 25600000);     // 51.2 MB
    unsigned short* bufB = (unsigned short*)(ws + (5120 << 10) + 76800000);     // 51.2 MB
    unsigned short* x_c = (unsigned short*)(ws + (5120 << 10) + 128000000);     // 16.8 MB

    const int nblk_edges = (N_EDGES + 255) / 256;
    const int nblk_nodes = (N_NODES + 255) / 256;
    const int nblk_rows4 = (N_NODES + 3) / 4;

    // ---- CSR + dinv ----
    hipMemsetAsync(cnt, 0, N_NODES * sizeof(int), stream);
    k_cnt_acc<<<nblk_edges, 256, 0, stream>>>(ei, cnt);
    k_scan1<<<NBLK_SCAN, 256, 0, stream>>>(cnt, off, part);
    k_scan2<<<1, 64, 0, stream>>>(part);
    k_scan3<<<nblk_nodes, 256, 0, stream>>>(off, part, cur, cnt, dinv);
    k_fill<<<nblk_edges, 256, 0, stream>>>(ei, dinv, cur, csr_src, csr_norm);

    // ---- merged prep: W conversions (W2/W3 sigma-permuted) + bounds + x conversion ----
    k_prep<<<PREP_BLOCKS, 256, 0, stream>>>(x, x_c, W1, Wb1, W2, Wb2, W3, Wb3, batch, gstart);

    // ---- layer 1: agg-first (Âx)W1 at K=128 (linear A), C in sigma-space ----
    k_aggx<<<nblk_rows4, 256, 0, stream>>>(x_c, dinv, off, cnt, csr_src, csr_norm, ag1_b);
    k_gemm_mfma<K1PAD><<<GEMM_GRID, 512, 0, stream>>>(ag1_b, Wb1, b1, bufA);

    // ---- layer 2 (sigma-space A, sigma-permuted W2) ----
    k_aggregate256<<<nblk_rows4, 256, 0, stream>>>(bufA, dinv, off, cnt, csr_src, csr_norm, bufB);
    k_gemm_mfma<HID><<<GEMM_GRID, 512, 0, stream>>>(bufB, Wb2, b2, bufA);

    // ---- layer 3 ----
    k_aggregate256<<<nblk_rows4, 256, 0, stream>>>(bufA, dinv, off, cnt, csr_src, csr_norm, bufB);
    k_gemm_mfma<HID><<<GEMM_GRID, 512, 0, stream>>>(bufB, Wb3, b3, bufA);

    // ---- pool (reads sigma-space, writes linear) ----
    k_pool2<<<N_GRAPHS, 128, 0, stream>>>(bufA, gstart, out);
}

// Round 18
// 254.629 us; speedup vs baseline: 1.0552x; 1.0552x over previous
//
#include <hip/hip_runtime.h>
#include <cstdint>
#include <cstddef>

#define N_NODES 100000
#define N_EDGES 300000
#define N_GRAPHS 2000
#define HID 256
#define INDIM 82
#define XCPAD 84     // compact bf16 x row (82 + 2 pad), 168 B
#define K1PAD 128
#define N_TILES ((N_NODES + 255) / 256)  // 391
#define SCAN_CHUNK 2048
#define NBLK_SCAN ((N_NODES + SCAN_CHUNK - 1) / SCAN_CHUNK)  // 49

typedef __bf16 bf16x8 __attribute__((ext_vector_type(8)));
typedef float f32x4 __attribute__((ext_vector_type(4)));

// native conversion: compiler emits v_cvt_pk_bf16_f32 (RNE) — do NOT hand-write bit math
__device__ __forceinline__ unsigned short f2bf(float f) {
    union { __bf16 h; unsigned short u; } v;
    v.h = (__bf16)f;
    return v.u;
}
__device__ __forceinline__ float bf2f(unsigned short s) {
    return __uint_as_float(((unsigned int)s) << 16);
}
// involution on [0,256): position p holds logical column sig(p) in sigma-space buffers
__device__ __forceinline__ int sig(int c) { return ((c & 15) << 4) | (c >> 4); }

// ---------------- degree counting ----------------
__global__ void k_cnt_acc(const int* __restrict__ ei, int* cnt) {
    int e = blockIdx.x * 256 + threadIdx.x;
    if (e < N_EDGES) atomicAdd(&cnt[ei[N_EDGES + e]], 1);
}

// ---------------- exclusive prefix sum ----------------
__global__ __launch_bounds__(256) void k_scan1(const int* __restrict__ cnt, int* __restrict__ off,
                                               int* __restrict__ partial) {
    __shared__ int sdata[256];
    const int base = blockIdx.x * SCAN_CHUNK;
    const int t = threadIdx.x;
    int v[8];
    int s = 0;
#pragma unroll
    for (int i = 0; i < 8; ++i) {
        int idx = base + t * 8 + i;
        v[i] = (idx < N_NODES) ? cnt[idx] : 0;
        s += v[i];
    }
    sdata[t] = s;
    __syncthreads();
    for (int d = 1; d < 256; d <<= 1) {
        int x = (t >= d) ? sdata[t - d] : 0;
        __syncthreads();
        sdata[t] += x;
        __syncthreads();
    }
    int run = sdata[t] - s;
#pragma unroll
    for (int i = 0; i < 8; ++i) {
        int idx = base + t * 8 + i;
        if (idx < N_NODES) off[idx] = run;
        run += v[i];
    }
    if (t == 255) partial[blockIdx.x] = sdata[255];
}

// wave-parallel exclusive scan of the 49 block partials (was serial 1-thread loop)
__global__ void k_scan2(int* partial) {
    int t = threadIdx.x;  // 64 lanes
    int v = (t < NBLK_SCAN) ? partial[t] : 0;
    int orig = v;
    for (int d = 1; d < 64; d <<= 1) {
        int u = __shfl_up(v, d);
        if (t >= d) v += u;
    }
    if (t < NBLK_SCAN) partial[t] = v - orig;  // exclusive
}

// scan fixup + cur init + dinv (merged)
__global__ void k_scan3(int* __restrict__ off, const int* __restrict__ partial,
                        int* __restrict__ cur, const int* __restrict__ cnt,
                        float* __restrict__ dinv) {
    int i = blockIdx.x * 256 + threadIdx.x;
    if (i < N_NODES) {
        int o = off[i] + partial[i >> 11];
        off[i] = o;
        cur[i] = o;
        dinv[i] = rsqrtf((float)cnt[i] + 1.0f);
    }
}

// CSR fill with precomputed edge norm
__global__ void k_fill(const int* __restrict__ ei, const float* __restrict__ dinv, int* cur,
                       int* __restrict__ csr_src, float* __restrict__ csr_norm) {
    int e = blockIdx.x * 256 + threadIdx.x;
    if (e < N_EDGES) {
        int s = ei[e];
        int d = ei[N_EDGES + e];
        int pos = atomicAdd(&cur[d], 1);
        csr_src[pos] = s;
        csr_norm[pos] = dinv[s] * dinv[d];
    }
}

// ---------------- merged prep: wconv x3 + graph bounds + x conversion ----------------
// PERM: Wb slot k (position-space) sources W[sig(k)] — matches sigma-space A rows.
__device__ __forceinline__ void wconv_body(const float* __restrict__ W,
                                           unsigned short* __restrict__ Wb, int KSRC, int i,
                                           bool perm) {
    // Wb fragment-contiguous: [kc][nt][lg][lr][j]; holds W[ksrc(kc*32+lg*8+j)][nt*16+lr]
    int kc = i >> 13;
    int r = i & 8191;
    int nt = r >> 9;
    int r2 = r & 511;
    int lg = r2 >> 7;
    int lr = (r2 >> 3) & 15;
    int j = r2 & 7;
    int k = kc * 32 + lg * 8 + j;
    if (perm) k = sig(k);
    int n = nt * 16 + lr;
    Wb[i] = (k < KSRC) ? f2bf(W[(size_t)k * HID + n]) : (unsigned short)0;
}

#define PREP_W1 128                      // 256*K1PAD/256
#define PREP_W23 256                     // 256*HID/256
#define PREP_BND 8                       // ceil(2001/256)
#define PREP_XC ((N_NODES * XCPAD + 255) / 256)
#define PREP_BLOCKS (PREP_W1 + 2 * PREP_W23 + PREP_BND + PREP_XC)

__global__ void k_prep(const float* __restrict__ x, unsigned short* __restrict__ xc,
                       const float* __restrict__ W1, unsigned short* __restrict__ Wb1,
                       const float* __restrict__ W2, unsigned short* __restrict__ Wb2,
                       const float* __restrict__ W3, unsigned short* __restrict__ Wb3,
                       const int* __restrict__ batch, int* __restrict__ gstart) {
    int b = blockIdx.x;
    int t = threadIdx.x;
    if (b < PREP_W1) { wconv_body(W1, Wb1, INDIM, b * 256 + t, false); return; }
    b -= PREP_W1;
    if (b < PREP_W23) { wconv_body(W2, Wb2, HID, b * 256 + t, true); return; }
    b -= PREP_W23;
    if (b < PREP_W23) { wconv_body(W3, Wb3, HID, b * 256 + t, true); return; }
    b -= PREP_W23;
    if (b < PREP_BND) {
        int g = b * 256 + t;
        if (g <= N_GRAPHS) {
            int lo = 0, hi = N_NODES;
            while (lo < hi) {
                int mid = (lo + hi) >> 1;
                if (batch[mid] < g) lo = mid + 1;
                else hi = mid;
            }
            gstart[g] = lo;
        }
        return;
    }
    b -= PREP_BND;
    int i = b * 256 + t;
    if (i < N_NODES * XCPAD) {
        int node = i / XCPAD;
        int k = i - node * XCPAD;
        xc[i] = (k < INDIM) ? f2bf(x[(size_t)node * INDIM + k]) : (unsigned short)0;
    }
}

// ---------------- MFMA GEMM: Cb = relu(A @ W + b), sigma-space C layout ----------------
// R16-proven (best config, 254.8 us): 512 threads = 8 waves x 32 rows = 256 rows/tile;
// whole W in LDS (one barrier); persistent grid of 256 blocks; barrier-free K-loop;
// A-frags hoisted; NO launch_bounds min-waves hint (R14/R17: VGPR caps cause spills).
// Five restructures (fusion, col-split, 1024t, reg-prefetch, XCD-paired half-W) all
// regressed — this is the local optimum. Epilogue stores thread's 16 per-row values
// contiguously at position lr*16+nt (sigma-involution): 2x uint4 vs 64 scattered 2B.
template <int K>
__global__ __launch_bounds__(512) void k_gemm_mfma(const unsigned short* __restrict__ A,
                                                   const unsigned short* __restrict__ Wb,
                                                   const float* __restrict__ bias,
                                                   unsigned short* __restrict__ Cb) {
    constexpr int NK = K / 32;
    __shared__ __align__(16) unsigned short Wsh[K * HID];  // 64 KB (K=128) / 128 KB (K=256)

    const int tid = threadIdx.x;
    const int w = tid >> 6;
    const int l = tid & 63;
    const int lr = l & 15;
    const int lg = l >> 4;

    // cooperative load of all of W into LDS (linear copy, fragment-ordered)
#pragma unroll
    for (int i = 0; i < K / 16; ++i) {
        int o = (i * 512 + tid) * 8;
        *reinterpret_cast<uint4*>(&Wsh[o]) = *reinterpret_cast<const uint4*>(Wb + o);
    }
    __syncthreads();

    float bv[16];
#pragma unroll
    for (int nt = 0; nt < 16; ++nt) bv[nt] = bias[nt * 16 + lr];

    for (int t = blockIdx.x; t < N_TILES; t += 256) {
        const int rowbase = t * 256 + w * 32;
        int r0 = rowbase + lr;
        int r1 = rowbase + 16 + lr;
        int r0c = r0 < N_NODES ? r0 : (N_NODES - 1);
        int r1c = r1 < N_NODES ? r1 : (N_NODES - 1);
        const unsigned short* a0p = A + (size_t)r0c * K + lg * 8;
        const unsigned short* a1p = A + (size_t)r1c * K + lg * 8;

        bf16x8 a0[NK], a1[NK];
#pragma unroll
        for (int kc = 0; kc < NK; ++kc) {
            a0[kc] = *reinterpret_cast<const bf16x8*>(a0p + kc * 32);
            a1[kc] = *reinterpret_cast<const bf16x8*>(a1p + kc * 32);
        }

        f32x4 acc0[16] = {};
        f32x4 acc1[16] = {};

#pragma unroll
        for (int kc = 0; kc < NK; ++kc) {
            const unsigned short* bfp = Wsh + kc * 8192 + l * 8;
#pragma unroll
            for (int nt = 0; nt < 16; ++nt) {
                bf16x8 bb = *reinterpret_cast<const bf16x8*>(bfp + nt * 512);
                acc0[nt] = __builtin_amdgcn_mfma_f32_16x16x32_bf16(a0[kc], bb, acc0[nt], 0, 0, 0);
                acc1[nt] = __builtin_amdgcn_mfma_f32_16x16x32_bf16(a1[kc], bb, acc1[nt], 0, 0, 0);
            }
        }

        // MFMA C layout: logical col = nt*16+lr, row = (lane>>4)*4 + j.
        // Store value at POSITION lr*16+nt -> 32 B contiguous per lane (sigma-space).
        int gr0 = rowbase + lg * 4;
#pragma unroll
        for (int j = 0; j < 4; ++j) {
            int gr = gr0 + j;
            if (gr < N_NODES) {
                unsigned short t0[16];
#pragma unroll
                for (int nt = 0; nt < 16; ++nt)
                    t0[nt] = f2bf(fmaxf(acc0[nt][j] + bv[nt], 0.0f));
                unsigned short* p = Cb + (size_t)gr * HID + lr * 16;
                *reinterpret_cast<uint4*>(p) = *reinterpret_cast<const uint4*>(t0);
                *reinterpret_cast<uint4*>(p + 8) = *reinterpret_cast<const uint4*>(t0 + 8);
            }
            int gr2 = gr + 16;
            if (gr2 < N_NODES) {
                unsigned short t1[16];
#pragma unroll
                for (int nt = 0; nt < 16; ++nt)
                    t1[nt] = f2bf(fmaxf(acc1[nt][j] + bv[nt], 0.0f));
                unsigned short* p = Cb + (size_t)gr2 * HID + lr * 16;
                *reinterpret_cast<uint4*>(p) = *reinterpret_cast<const uint4*>(t1);
                *reinterpret_cast<uint4*>(p + 8) = *reinterpret_cast<const uint4*>(t1 + 8);
            }
        }
    }
}

// ---------------- aggregate: ob = bf16(dinv^2*in_self + sum norm*in[src]) ----------------
// Position-wise (works identically in sigma-space). At the 6.3 TB/s logical streaming
// ceiling (measured R9/R10/R16) — do not touch.
__global__ void k_aggregate256(const unsigned short* __restrict__ tb,
                               const float* __restrict__ dinv, const int* __restrict__ off,
                               const int* __restrict__ cnt, const int* __restrict__ csr_src,
                               const float* __restrict__ csr_norm,
                               unsigned short* __restrict__ ob) {
    int node = blockIdx.x * 4 + (threadIdx.x >> 6);
    if (node >= N_NODES) return;
    int lane = threadIdx.x & 63;
    const size_t lo = (size_t)lane * 4;
    int o0 = off[node];
    int n = cnt[node];
    float di = dinv[node];
    float s2 = di * di;
    ushort4 sv = *reinterpret_cast<const ushort4*>(&tb[(size_t)node * HID + lo]);
    float4 acc = {bf2f(sv.x) * s2, bf2f(sv.y) * s2, bf2f(sv.z) * s2, bf2f(sv.w) * s2};

    int j = 0;
    for (; j + 3 < n; j += 4) {
        int s0 = csr_src[o0 + j];
        int s1 = csr_src[o0 + j + 1];
        int s2i = csr_src[o0 + j + 2];
        int s3 = csr_src[o0 + j + 3];
        float n0 = csr_norm[o0 + j];
        float n1 = csr_norm[o0 + j + 1];
        float n2 = csr_norm[o0 + j + 2];
        float n3 = csr_norm[o0 + j + 3];
        ushort4 u0 = *reinterpret_cast<const ushort4*>(&tb[(size_t)s0 * HID + lo]);
        ushort4 u1 = *reinterpret_cast<const ushort4*>(&tb[(size_t)s1 * HID + lo]);
        ushort4 u2 = *reinterpret_cast<const ushort4*>(&tb[(size_t)s2i * HID + lo]);
        ushort4 u3 = *reinterpret_cast<const ushort4*>(&tb[(size_t)s3 * HID + lo]);
        acc.x = fmaf(n0, bf2f(u0.x), acc.x); acc.y = fmaf(n0, bf2f(u0.y), acc.y);
        acc.z = fmaf(n0, bf2f(u0.z), acc.z); acc.w = fmaf(n0, bf2f(u0.w), acc.w);
        acc.x = fmaf(n1, bf2f(u1.x), acc.x); acc.y = fmaf(n1, bf2f(u1.y), acc.y);
        acc.z = fmaf(n1, bf2f(u1.z), acc.z); acc.w = fmaf(n1, bf2f(u1.w), acc.w);
        acc.x = fmaf(n2, bf2f(u2.x), acc.x); acc.y = fmaf(n2, bf2f(u2.y), acc.y);
        acc.z = fmaf(n2, bf2f(u2.z), acc.z); acc.w = fmaf(n2, bf2f(u2.w), acc.w);
        acc.x = fmaf(n3, bf2f(u3.x), acc.x); acc.y = fmaf(n3, bf2f(u3.y), acc.y);
        acc.z = fmaf(n3, bf2f(u3.z), acc.z); acc.w = fmaf(n3, bf2f(u3.w), acc.w);
    }
    int rem = n - j;
    if (rem & 2) {
        int s0 = csr_src[o0 + j];
        int s1 = csr_src[o0 + j + 1];
        float n0 = csr_norm[o0 + j];
        float n1 = csr_norm[o0 + j + 1];
        ushort4 u0 = *reinterpret_cast<const ushort4*>(&tb[(size_t)s0 * HID + lo]);
        ushort4 u1 = *reinterpret_cast<const ushort4*>(&tb[(size_t)s1 * HID + lo]);
        acc.x = fmaf(n0, bf2f(u0.x), acc.x); acc.y = fmaf(n0, bf2f(u0.y), acc.y);
        acc.z = fmaf(n0, bf2f(u0.z), acc.z); acc.w = fmaf(n0, bf2f(u0.w), acc.w);
        acc.x = fmaf(n1, bf2f(u1.x), acc.x); acc.y = fmaf(n1, bf2f(u1.y), acc.y);
        acc.z = fmaf(n1, bf2f(u1.z), acc.z); acc.w = fmaf(n1, bf2f(u1.w), acc.w);
        j += 2;
    }
    if (rem & 1) {
        int s0 = csr_src[o0 + j];
        float n0 = csr_norm[o0 + j];
        ushort4 u0 = *reinterpret_cast<const ushort4*>(&tb[(size_t)s0 * HID + lo]);
        acc.x = fmaf(n0, bf2f(u0.x), acc.x); acc.y = fmaf(n0, bf2f(u0.y), acc.y);
        acc.z = fmaf(n0, bf2f(u0.z), acc.z); acc.w = fmaf(n0, bf2f(u0.w), acc.w);
    }
    ushort4 o;
    o.x = f2bf(acc.x);
    o.y = f2bf(acc.y);
    o.z = f2bf(acc.z);
    o.w = f2bf(acc.w);
    *reinterpret_cast<ushort4*>(&ob[(size_t)node * HID + lo]) = o;
}

// layer-1: aggregate compact bf16 x [N,84] -> padded bf16 [N,128] GEMM input (linear k)
__global__ void k_aggx(const unsigned short* __restrict__ xc,
                       const float* __restrict__ dinv, const int* __restrict__ off,
                       const int* __restrict__ cnt, const int* __restrict__ csr_src,
                       const float* __restrict__ csr_norm,
                       unsigned short* __restrict__ ob) {
    int node = blockIdx.x * 4 + (threadIdx.x >> 6);
    if (node >= N_NODES) return;
    int lane = threadIdx.x & 63;
    const bool act = lane < (XCPAD / 2);  // 42 lanes cover 84 cols
    const size_t co = (size_t)lane * 2;
    int o0 = off[node];
    int n = cnt[node];
    float di = dinv[node];
    float s2 = di * di;
    float2 acc = {0.0f, 0.0f};
    if (act) {
        ushort2 sv = *reinterpret_cast<const ushort2*>(&xc[(size_t)node * XCPAD + co]);
        acc.x = bf2f(sv.x) * s2;
        acc.y = bf2f(sv.y) * s2;
    }
    int j = 0;
    for (; j + 3 < n; j += 4) {
        int s0 = csr_src[o0 + j];
        int s1 = csr_src[o0 + j + 1];
        int s2i = csr_src[o0 + j + 2];
        int s3 = csr_src[o0 + j + 3];
        float n0 = csr_norm[o0 + j];
        float n1 = csr_norm[o0 + j + 1];
        float n2 = csr_norm[o0 + j + 2];
        float n3 = csr_norm[o0 + j + 3];
        if (act) {
            ushort2 u0 = *reinterpret_cast<const ushort2*>(&xc[(size_t)s0 * XCPAD + co]);
            ushort2 u1 = *reinterpret_cast<const ushort2*>(&xc[(size_t)s1 * XCPAD + co]);
            ushort2 u2 = *reinterpret_cast<const ushort2*>(&xc[(size_t)s2i * XCPAD + co]);
            ushort2 u3 = *reinterpret_cast<const ushort2*>(&xc[(size_t)s3 * XCPAD + co]);
            acc.x = fmaf(n0, bf2f(u0.x), acc.x); acc.y = fmaf(n0, bf2f(u0.y), acc.y);
            acc.x = fmaf(n1, bf2f(u1.x), acc.x); acc.y = fmaf(n1, bf2f(u1.y), acc.y);
            acc.x = fmaf(n2, bf2f(u2.x), acc.x); acc.y = fmaf(n2, bf2f(u2.y), acc.y);
            acc.x = fmaf(n3, bf2f(u3.x), acc.x); acc.y = fmaf(n3, bf2f(u3.y), acc.y);
        }
    }
    int rem = n - j;
    if (rem & 2) {
        int s0 = csr_src[o0 + j];
        int s1 = csr_src[o0 + j + 1];
        float n0 = csr_norm[o0 + j];
        float n1 = csr_norm[o0 + j + 1];
        if (act) {
            ushort2 u0 = *reinterpret_cast<const ushort2*>(&xc[(size_t)s0 * XCPAD + co]);
            ushort2 u1 = *reinterpret_cast<const ushort2*>(&xc[(size_t)s1 * XCPAD + co]);
            acc.x = fmaf(n0, bf2f(u0.x), acc.x); acc.y = fmaf(n0, bf2f(u0.y), acc.y);
            acc.x = fmaf(n1, bf2f(u1.x), acc.x); acc.y = fmaf(n1, bf2f(u1.y), acc.y);
        }
        j += 2;
    }
    if (rem & 1) {
        int s0 = csr_src[o0 + j];
        float n0 = csr_norm[o0 + j];
        if (act) {
            ushort2 u0 = *reinterpret_cast<const ushort2*>(&xc[(size_t)s0 * XCPAD + co]);
            acc.x = fmaf(n0, bf2f(u0.x), acc.x); acc.y = fmaf(n0, bf2f(u0.y), acc.y);
        }
    }
    ushort2 o;
    o.x = f2bf(acc.x);
    o.y = f2bf(acc.y);
    *reinterpret_cast<ushort2*>(&ob[(size_t)node * K1PAD + co]) = o;  // all 64 lanes: pad zeroed
}

// ---------------- pool: 2 waves per graph; input sigma-space, output linear ----------------
__global__ void k_pool2(const unsigned short* __restrict__ hb, const int* __restrict__ gstart,
                        float* __restrict__ out) {
    int g = blockIdx.x;
    int w = threadIdx.x >> 6;
    int lane = threadIdx.x & 63;
    int p = w * 128 + lane * 2;  // position in sigma-space
    int s = gstart[g], e = gstart[g + 1];
    float2 m = {0.0f, 0.0f};  // h >= 0 after relu
    for (int i = s; i < e; ++i) {
        ushort2 u = *reinterpret_cast<const ushort2*>(&hb[(size_t)i * HID + p]);
        m.x = fmaxf(m.x, bf2f(u.x));
        m.y = fmaxf(m.y, bf2f(u.y));
    }
    // un-permute: position p holds logical column sig(p)
    out[(size_t)g * HID + sig(p)] = m.x;
    out[(size_t)g * HID + sig(p + 1)] = m.y;
}

extern "C" void kernel_launch(void* const* d_in, const int* in_sizes, int n_in,
                              void* d_out, int out_size, void* d_ws, size_t ws_size,
                              hipStream_t stream) {
    const float* x = (const float*)d_in[0];
    const int* ei = (const int*)d_in[1];
    const int* batch = (const int*)d_in[2];
    const float* W1 = (const float*)d_in[4];
    const float* b1 = (const float*)d_in[5];
    const float* W2 = (const float*)d_in[6];
    const float* b2 = (const float*)d_in[7];
    const float* W3 = (const float*)d_in[8];
    const float* b3 = (const float*)d_in[9];
    float* out = (float*)d_out;

    // workspace layout (~150 MB, R10/R16-proven)
    char* ws = (char*)d_ws;
    float* dinv = (float*)(ws);
    int* cnt = (int*)(ws + (512 << 10));
    int* off = (int*)(ws + (1024 << 10));
    int* cur = (int*)(ws + (1536 << 10));
    int* part = (int*)(ws + (2048 << 10));
    int* gstart = (int*)(ws + (2048 << 10) + 4096);
    int* csr_src = (int*)(ws + (2176 << 10));        // 1.2 MB
    float* csr_norm = (float*)(ws + (3392 << 10));   // 1.2 MB
    unsigned short* Wb1 = (unsigned short*)(ws + (4608 << 10));   // 64 KB
    unsigned short* Wb2 = (unsigned short*)(ws + (4736 << 10));   // 128 KB
    unsigned short* Wb3 = (unsigned short*)(ws + (4928 << 10));   // 128 KB
    unsigned short* ag1_b = (unsigned short*)(ws + (5120 << 10));               // 25.6 MB
    unsigned short* bufA = (unsigned short*)(ws + (5120 << 10) + 25600000);     // 51.2 MB
    unsigned short* bufB = (unsigned short*)(ws + (5120 << 10) + 76800000);     // 51.2 MB
    unsigned short* x_c = (unsigned short*)(ws + (5120 << 10) + 128000000);     // 16.8 MB

    const int nblk_edges = (N_EDGES + 255) / 256;
    const int nblk_nodes = (N_NODES + 255) / 256;
    const int nblk_rows4 = (N_NODES + 3) / 4;

    // ---- CSR + dinv ----
    hipMemsetAsync(cnt, 0, N_NODES * sizeof(int), stream);
    k_cnt_acc<<<nblk_edges, 256, 0, stream>>>(ei, cnt);
    k_scan1<<<NBLK_SCAN, 256, 0, stream>>>(cnt, off, part);
    k_scan2<<<1, 64, 0, stream>>>(part);
    k_scan3<<<nblk_nodes, 256, 0, stream>>>(off, part, cur, cnt, dinv);
    k_fill<<<nblk_edges, 256, 0, stream>>>(ei, dinv, cur, csr_src, csr_norm);

    // ---- merged prep: W conversions (W2/W3 sigma-permuted) + bounds + x conversion ----
    k_prep<<<PREP_BLOCKS, 256, 0, stream>>>(x, x_c, W1, Wb1, W2, Wb2, W3, Wb3, batch, gstart);

    // ---- layer 1: agg-first (Âx)W1 at K=128 (linear A), C in sigma-space ----
    k_aggx<<<nblk_rows4, 256, 0, stream>>>(x_c, dinv, off, cnt, csr_src, csr_norm, ag1_b);
    k_gemm_mfma<K1PAD><<<256, 512, 0, stream>>>(ag1_b, Wb1, b1, bufA);

    // ---- layer 2 (sigma-space A, sigma-permuted W2) ----
    k_aggregate256<<<nblk_rows4, 256, 0, stream>>>(bufA, dinv, off, cnt, csr_src, csr_norm, bufB);
    k_gemm_mfma<HID><<<256, 512, 0, stream>>>(bufB, Wb2, b2, bufA);

    // ---- layer 3 ----
    k_aggregate256<<<nblk_rows4, 256, 0, stream>>>(bufA, dinv, off, cnt, csr_src, csr_norm, bufB);
    k_gemm_mfma<HID><<<256, 512, 0, stream>>>(bufB, Wb3, b3, bufA);

    // ---- pool (reads sigma-space, writes linear) ----
    k_pool2<<<N_GRAPHS, 128, 0, stream>>>(bufA, gstart, out);
}